// Round 1
// baseline (1016.348 us; speedup 1.0000x reference)
//
#include <hip/hip_runtime.h>

constexpr int K_DIM = 128;

// ---------- CSR build ----------
__global__ void init_deg_k(int* __restrict__ deg, int n) {
  int t = blockIdx.x * blockDim.x + threadIdx.x;
  if (t < n) deg[t] = 1;  // self loop
}

__global__ void count_k(const int* __restrict__ dst, int E, int* __restrict__ deg) {
  int t = blockIdx.x * blockDim.x + threadIdx.x;
  if (t < E) atomicAdd(&deg[dst[t]], 1);
}

__global__ __launch_bounds__(1024) void scan_k(const int* __restrict__ deg,
    int* __restrict__ rowptr, int* __restrict__ cursor, float* __restrict__ dinv, int n) {
  __shared__ int part[1024];
  const int tid = threadIdx.x;
  const int chunk = (n + 1023) >> 10;
  const int s = tid * chunk;
  const int e = (s + chunk < n) ? (s + chunk) : n;
  int sum = 0;
  for (int i = s; i < e; ++i) sum += deg[i];
  part[tid] = sum;
  __syncthreads();
  for (int off = 1; off < 1024; off <<= 1) {
    int v = part[tid];
    int w = (tid >= off) ? part[tid - off] : 0;
    __syncthreads();
    part[tid] = v + w;
    __syncthreads();
  }
  int run = (tid > 0) ? part[tid - 1] : 0;
  for (int i = s; i < e; ++i) {
    int d = deg[i];
    rowptr[i] = run;
    cursor[i] = run;
    dinv[i] = rsqrtf((float)d);
    run += d;
  }
  if (tid == 1023) rowptr[n] = part[1023];
}

__global__ void scatter_k(const int* __restrict__ ei, int E, int n,
    int* __restrict__ cursor, int* __restrict__ colidx) {
  int t = blockIdx.x * blockDim.x + threadIdx.x;
  if (t < E) {
    int s = ei[t];
    int d = ei[E + t];
    int p = atomicAdd(&cursor[d], 1);
    colidx[p] = s;
  } else if (t < E + n) {
    int i = t - E;
    int p = atomicAdd(&cursor[i], 1);
    colidx[p] = i;
  }
}

// ---------- fp32 GEMM: C[n x NOUT] = X[n x 128] @ W[128 x NOUT] ----------
// BM=64 rows/block, 256 threads, micro-tile 4 rows x MC cols.
template<int NOUT, int MC>
__global__ __launch_bounds__(256) void gemm_k(const float* __restrict__ X,
    const float* __restrict__ W, float* __restrict__ C, int n) {
  __shared__ float Xs[64][K_DIM + 4];
  __shared__ float Ws[K_DIM][NOUT];
  const int tid = threadIdx.x;
  const int row0 = blockIdx.x * 64;

  constexpr int WF4 = K_DIM * NOUT / 4;
  for (int v = tid; v < WF4; v += 256) {
    float4 w4 = reinterpret_cast<const float4*>(W)[v];
    int r = v / (NOUT / 4), c4 = v % (NOUT / 4);
    *reinterpret_cast<float4*>(&Ws[r][c4 * 4]) = w4;
  }
  constexpr int XF4 = 64 * K_DIM / 4;
  for (int v = tid; v < XF4; v += 256) {
    int r = v / (K_DIM / 4), c4 = v % (K_DIM / 4);
    int gr = row0 + r;
    float4 x4 = make_float4(0.f, 0.f, 0.f, 0.f);
    if (gr < n) x4 = reinterpret_cast<const float4*>(X)[(size_t)gr * (K_DIM / 4) + c4];
    *reinterpret_cast<float4*>(&Xs[r][c4 * 4]) = x4;
  }
  __syncthreads();

  const int rg = tid >> 4, cg = tid & 15;   // 16 rowgroups x 16 colgroups
  const int r0 = rg * 4;
  const int c0 = cg * MC;
  float acc[4][MC];
  #pragma unroll
  for (int i = 0; i < 4; ++i)
    #pragma unroll
    for (int j = 0; j < MC; ++j) acc[i][j] = 0.f;

  #pragma unroll 4
  for (int k = 0; k < K_DIM; ++k) {
    float a[4];
    #pragma unroll
    for (int i = 0; i < 4; ++i) a[i] = Xs[r0 + i][k];
    float b[MC];
    #pragma unroll
    for (int j = 0; j < MC; j += 4) {
      float4 t4 = *reinterpret_cast<const float4*>(&Ws[k][c0 + j]);
      b[j] = t4.x; b[j + 1] = t4.y; b[j + 2] = t4.z; b[j + 3] = t4.w;
    }
    #pragma unroll
    for (int i = 0; i < 4; ++i)
      #pragma unroll
      for (int j = 0; j < MC; ++j)
        acc[i][j] = fmaf(a[i], b[j], acc[i][j]);
  }

  #pragma unroll
  for (int i = 0; i < 4; ++i) {
    int gr = row0 + r0 + i;
    if (gr < n) {
      #pragma unroll
      for (int j = 0; j < MC; j += 4) {
        float4 t4 = make_float4(acc[i][j], acc[i][j + 1], acc[i][j + 2], acc[i][j + 3]);
        reinterpret_cast<float4*>(C)[((size_t)gr * NOUT + c0 + j) >> 2] = t4;
      }
    }
  }
}

// ---------- CSR aggregation: out[i] = dinv[i] * sum_j dinv[c_j]*H[c_j] + b ----------
// one wave per node; lane = feature (pair).
template<int NOUT, bool RELU>
__global__ __launch_bounds__(256) void agg_k(const float* __restrict__ H,
    const int* __restrict__ rowptr, const int* __restrict__ colidx,
    const float* __restrict__ dinv, const float* __restrict__ bias,
    float* __restrict__ out, int n) {
  const int wave = threadIdx.x >> 6;
  const int lane = threadIdx.x & 63;
  const int node = blockIdx.x * 4 + wave;
  if (node >= n) return;
  const int s = rowptr[node], e = rowptr[node + 1];

  if constexpr (NOUT == 128) {
    const float2* H2 = reinterpret_cast<const float2*>(H);
    float ax = 0.f, ay = 0.f;
    int j = s;
    for (; j + 1 < e; j += 2) {
      int c0 = colidx[j], c1 = colidx[j + 1];
      float d0 = dinv[c0], d1 = dinv[c1];
      float2 h0 = H2[(size_t)c0 * 64 + lane];
      float2 h1 = H2[(size_t)c1 * 64 + lane];
      ax = fmaf(d0, h0.x, ax); ay = fmaf(d0, h0.y, ay);
      ax = fmaf(d1, h1.x, ax); ay = fmaf(d1, h1.y, ay);
    }
    if (j < e) {
      int c0 = colidx[j];
      float d0 = dinv[c0];
      float2 h0 = H2[(size_t)c0 * 64 + lane];
      ax = fmaf(d0, h0.x, ax); ay = fmaf(d0, h0.y, ay);
    }
    float di = dinv[node];
    float2 b2 = reinterpret_cast<const float2*>(bias)[lane];
    float ox = fmaf(di, ax, b2.x), oy = fmaf(di, ay, b2.y);
    if (RELU) { ox = fmaxf(ox, 0.f); oy = fmaxf(oy, 0.f); }
    reinterpret_cast<float2*>(out)[(size_t)node * 64 + lane] = make_float2(ox, oy);
  } else {
    float a0 = 0.f;
    int j = s;
    for (; j + 1 < e; j += 2) {
      int c0 = colidx[j], c1 = colidx[j + 1];
      float d0 = dinv[c0], d1 = dinv[c1];
      float h0 = H[(size_t)c0 * NOUT + lane];
      float h1 = H[(size_t)c1 * NOUT + lane];
      a0 = fmaf(d0, h0, a0);
      a0 = fmaf(d1, h1, a0);
    }
    if (j < e) {
      int c0 = colidx[j];
      a0 = fmaf(dinv[c0], H[(size_t)c0 * NOUT + lane], a0);
    }
    float o = fmaf(dinv[node], a0, bias[lane]);
    if (RELU) o = fmaxf(o, 0.f);
    out[(size_t)node * NOUT + lane] = o;
  }
}

extern "C" void kernel_launch(void* const* d_in, const int* in_sizes, int n_in,
                              void* d_out, int out_size, void* d_ws, size_t ws_size,
                              hipStream_t stream) {
  const int n = in_sizes[0] / K_DIM;   // 50000
  const int E = in_sizes[1] / 2;       // 1600000

  const float* x  = (const float*)d_in[0];
  const int*   ei = (const int*)d_in[1];
  const float* W1 = (const float*)d_in[2];
  const float* b1 = (const float*)d_in[3];
  const float* W2 = (const float*)d_in[4];
  const float* b2 = (const float*)d_in[5];
  const float* W3 = (const float*)d_in[6];
  const float* b3 = (const float*)d_in[7];
  const float* W4 = (const float*)d_in[8];
  const float* b4 = (const float*)d_in[9];
  float* out = (float*)d_out;

  char* ws = (char*)d_ws;
  size_t off = 0;
  auto alloc = [&](size_t bytes) -> void* {
    void* p = ws + off;
    off += (bytes + 255) & ~(size_t)255;
    return p;
  };
  int*   deg    = (int*)  alloc((size_t)n * 4);
  float* dinv   = (float*)alloc((size_t)n * 4);
  int*   rowptr = (int*)  alloc((size_t)(n + 1) * 4);
  int*   cursor = (int*)  alloc((size_t)n * 4);
  int*   colidx = (int*)  alloc((size_t)(E + n) * 4);
  float* hA     = (float*)alloc((size_t)n * 128 * 4);
  float* hB     = (float*)alloc((size_t)n * 128 * 4);

  // CSR build
  init_deg_k<<<(n + 255) / 256, 256, 0, stream>>>(deg, n);
  count_k<<<(E + 255) / 256, 256, 0, stream>>>(ei + E, E, deg);
  scan_k<<<1, 1024, 0, stream>>>(deg, rowptr, cursor, dinv, n);
  scatter_k<<<(E + n + 255) / 256, 256, 0, stream>>>(ei, E, n, cursor, colidx);

  const int gb = (n + 63) / 64;   // gemm blocks
  const int ab = (n + 3) / 4;     // agg blocks

  // layer 1
  gemm_k<128, 8><<<gb, 256, 0, stream>>>(x, W1, hA, n);
  agg_k<128, true><<<ab, 256, 0, stream>>>(hA, rowptr, colidx, dinv, b1, hB, n);
  // layer 2
  gemm_k<128, 8><<<gb, 256, 0, stream>>>(hB, W2, hA, n);
  agg_k<128, true><<<ab, 256, 0, stream>>>(hA, rowptr, colidx, dinv, b2, hB, n);
  // layer 3
  gemm_k<128, 8><<<gb, 256, 0, stream>>>(hB, W3, hA, n);
  agg_k<128, true><<<ab, 256, 0, stream>>>(hA, rowptr, colidx, dinv, b3, hB, n);
  // layer 4 (128 -> 64, no relu, write d_out)
  gemm_k<64, 4><<<gb, 256, 0, stream>>>(hB, W4, hA, n);
  agg_k<64, false><<<ab, 256, 0, stream>>>(hA, rowptr, colidx, dinv, b4, out, n);
}

// Round 2
// 694.916 us; speedup vs baseline: 1.4625x; 1.4625x over previous
//
#include <hip/hip_runtime.h>
#include <hip/hip_fp16.h>

constexpr int K_DIM = 128;

// ---------- CSR build ----------
__global__ void init_deg_k(int* __restrict__ deg, int n) {
  int t = blockIdx.x * blockDim.x + threadIdx.x;
  if (t < n) deg[t] = 1;  // self loop
}

__global__ void count_k(const int* __restrict__ dst, int E, int* __restrict__ deg) {
  int t = blockIdx.x * blockDim.x + threadIdx.x;
  if (t < E) atomicAdd(&deg[dst[t]], 1);
}

__global__ __launch_bounds__(1024) void scan_k(const int* __restrict__ deg,
    int* __restrict__ rowptr, int* __restrict__ cursor, float* __restrict__ dinv, int n) {
  __shared__ int part[1024];
  const int tid = threadIdx.x;
  const int chunk = (n + 1023) >> 10;
  const int s = tid * chunk;
  const int e = (s + chunk < n) ? (s + chunk) : n;
  int sum = 0;
  for (int i = s; i < e; ++i) sum += deg[i];
  part[tid] = sum;
  __syncthreads();
  for (int off = 1; off < 1024; off <<= 1) {
    int v = part[tid];
    int w = (tid >= off) ? part[tid - off] : 0;
    __syncthreads();
    part[tid] = v + w;
    __syncthreads();
  }
  int run = (tid > 0) ? part[tid - 1] : 0;
  for (int i = s; i < e; ++i) {
    int d = deg[i];
    rowptr[i] = run;
    cursor[i] = run;
    dinv[i] = rsqrtf((float)d);
    run += d;
  }
  if (tid == 1023) rowptr[n] = part[1023];
}

__global__ void scatter_k(const int* __restrict__ ei, int E, int n,
    int* __restrict__ cursor, int* __restrict__ colidx) {
  int t = blockIdx.x * blockDim.x + threadIdx.x;
  if (t < E) {
    int s = ei[t];
    int d = ei[E + t];
    int p = atomicAdd(&cursor[d], 1);
    colidx[p] = s;
  } else if (t < E + n) {
    int i = t - E;
    int p = atomicAdd(&cursor[i], 1);
    colidx[p] = i;
  }
}

// ---------- fp32 GEMM -> fp16 out: H[n x NOUT] = X[n x 128] @ W[128 x NOUT] ----------
// 64 rows/block, 256 threads, K chunked at 32 (LDS 24.8 KB -> 6 blocks/CU).
// Thread tile: 4 rows x MC cols; cols are {4*cg..+3} (+ {64+4*cg..+3} for NOUT=128)
// so each wave's ds_read_b128 covers a contiguous 256 B (2-way alias only = free).
template<int NOUT>
__global__ __launch_bounds__(256) void gemm_k(const float* __restrict__ X,
    const float* __restrict__ W, __half* __restrict__ H, int n) {
  constexpr int KC = 32;
  constexpr int MC = (NOUT == 128) ? 8 : 4;
  __shared__ float Xs[64][KC + 1];
  __shared__ float Ws[KC][NOUT];
  const int tid = threadIdx.x;
  const int row0 = blockIdx.x * 64;
  const int rg = tid >> 4;       // 0..15
  const int cg = tid & 15;       // 0..15
  const int r0 = rg * 4;

  float acc[4][MC];
  #pragma unroll
  for (int i = 0; i < 4; ++i)
    #pragma unroll
    for (int j = 0; j < MC; ++j) acc[i][j] = 0.f;

  for (int kc = 0; kc < K_DIM; kc += KC) {
    __syncthreads();
    // stage Xs chunk: 64 x 32 floats = 512 float4
    #pragma unroll
    for (int v = tid; v < 64 * KC / 4; v += 256) {
      int r = v / (KC / 4), c4 = v % (KC / 4);
      int gr = row0 + r;
      float4 x4 = make_float4(0.f, 0.f, 0.f, 0.f);
      if (gr < n)
        x4 = reinterpret_cast<const float4*>(X)[(size_t)gr * (K_DIM / 4) + (kc / 4) + c4];
      *reinterpret_cast<float4*>(&Xs[r][c4 * 4]) = x4;
    }
    // stage Ws chunk: 32 x NOUT floats
    #pragma unroll
    for (int v = tid; v < KC * NOUT / 4; v += 256) {
      int r = v / (NOUT / 4), c4 = v % (NOUT / 4);
      float4 w4 = reinterpret_cast<const float4*>(W)[(size_t)(kc + r) * (NOUT / 4) + c4];
      *reinterpret_cast<float4*>(&Ws[r][c4 * 4]) = w4;
    }
    __syncthreads();

    #pragma unroll 8
    for (int k = 0; k < KC; ++k) {
      float a[4];
      #pragma unroll
      for (int i = 0; i < 4; ++i) a[i] = Xs[r0 + i][k];
      float b[MC];
      float4 b0 = *reinterpret_cast<const float4*>(&Ws[k][cg * 4]);
      b[0] = b0.x; b[1] = b0.y; b[2] = b0.z; b[3] = b0.w;
      if constexpr (NOUT == 128) {
        float4 b1 = *reinterpret_cast<const float4*>(&Ws[k][64 + cg * 4]);
        b[4] = b1.x; b[5] = b1.y; b[6] = b1.z; b[7] = b1.w;
      }
      #pragma unroll
      for (int i = 0; i < 4; ++i)
        #pragma unroll
        for (int j = 0; j < MC; ++j)
          acc[i][j] = fmaf(a[i], b[j], acc[i][j]);
    }
  }

  #pragma unroll
  for (int i = 0; i < 4; ++i) {
    int gr = row0 + r0 + i;
    if (gr < n) {
      union { __half2 h[2]; float2 f; } u0;
      u0.h[0] = __floats2half2_rn(acc[i][0], acc[i][1]);
      u0.h[1] = __floats2half2_rn(acc[i][2], acc[i][3]);
      *reinterpret_cast<float2*>(&H[(size_t)gr * NOUT + cg * 4]) = u0.f;
      if constexpr (NOUT == 128) {
        union { __half2 h[2]; float2 f; } u1;
        u1.h[0] = __floats2half2_rn(acc[i][4], acc[i][5]);
        u1.h[1] = __floats2half2_rn(acc[i][6], acc[i][7]);
        *reinterpret_cast<float2*>(&H[(size_t)gr * NOUT + 64 + cg * 4]) = u1.f;
      }
    }
  }
}

// ---------- CSR aggregation (fp16 gather, fp32 accum) ----------
// out[i] = dinv[i] * sum_j dinv[c_j]*H[c_j] + b ; one wave per node.
template<bool RELU>
__global__ __launch_bounds__(256) void agg128_k(const __half* __restrict__ H,
    const int* __restrict__ rowptr, const int* __restrict__ colidx,
    const float* __restrict__ dinv, const float* __restrict__ bias,
    float* __restrict__ out, int n) {
  const int wave = threadIdx.x >> 6;
  const int lane = threadIdx.x & 63;
  const int node = blockIdx.x * 4 + wave;
  if (node >= n) return;
  const int s = rowptr[node], e = rowptr[node + 1];
  const __half2* H2 = reinterpret_cast<const __half2*>(H);

  float ax = 0.f, ay = 0.f;
  int j = s;
  for (; j + 3 < e; j += 4) {
    int c0 = colidx[j], c1 = colidx[j + 1], c2 = colidx[j + 2], c3 = colidx[j + 3];
    float d0 = dinv[c0], d1 = dinv[c1], d2 = dinv[c2], d3 = dinv[c3];
    float2 h0 = __half22float2(H2[(size_t)c0 * 64 + lane]);
    float2 h1 = __half22float2(H2[(size_t)c1 * 64 + lane]);
    float2 h2 = __half22float2(H2[(size_t)c2 * 64 + lane]);
    float2 h3 = __half22float2(H2[(size_t)c3 * 64 + lane]);
    ax = fmaf(d0, h0.x, ax); ay = fmaf(d0, h0.y, ay);
    ax = fmaf(d1, h1.x, ax); ay = fmaf(d1, h1.y, ay);
    ax = fmaf(d2, h2.x, ax); ay = fmaf(d2, h2.y, ay);
    ax = fmaf(d3, h3.x, ax); ay = fmaf(d3, h3.y, ay);
  }
  for (; j < e; ++j) {
    int c0 = colidx[j];
    float d0 = dinv[c0];
    float2 h0 = __half22float2(H2[(size_t)c0 * 64 + lane]);
    ax = fmaf(d0, h0.x, ax); ay = fmaf(d0, h0.y, ay);
  }
  float di = dinv[node];
  float2 b2 = reinterpret_cast<const float2*>(bias)[lane];
  float ox = fmaf(di, ax, b2.x), oy = fmaf(di, ay, b2.y);
  if (RELU) { ox = fmaxf(ox, 0.f); oy = fmaxf(oy, 0.f); }
  reinterpret_cast<float2*>(out)[(size_t)node * 64 + lane] = make_float2(ox, oy);
}

__global__ __launch_bounds__(256) void agg64_k(const __half* __restrict__ H,
    const int* __restrict__ rowptr, const int* __restrict__ colidx,
    const float* __restrict__ dinv, const float* __restrict__ bias,
    float* __restrict__ out, int n) {
  const int wave = threadIdx.x >> 6;
  const int lane = threadIdx.x & 63;
  const int node = blockIdx.x * 4 + wave;
  if (node >= n) return;
  const int s = rowptr[node], e = rowptr[node + 1];

  float a0 = 0.f;
  int j = s;
  for (; j + 3 < e; j += 4) {
    int c0 = colidx[j], c1 = colidx[j + 1], c2 = colidx[j + 2], c3 = colidx[j + 3];
    float d0 = dinv[c0], d1 = dinv[c1], d2 = dinv[c2], d3 = dinv[c3];
    float h0 = __half2float(H[(size_t)c0 * 64 + lane]);
    float h1 = __half2float(H[(size_t)c1 * 64 + lane]);
    float h2 = __half2float(H[(size_t)c2 * 64 + lane]);
    float h3 = __half2float(H[(size_t)c3 * 64 + lane]);
    a0 = fmaf(d0, h0, a0);
    a0 = fmaf(d1, h1, a0);
    a0 = fmaf(d2, h2, a0);
    a0 = fmaf(d3, h3, a0);
  }
  for (; j < e; ++j) {
    int c0 = colidx[j];
    a0 = fmaf(dinv[c0], __half2float(H[(size_t)c0 * 64 + lane]), a0);
  }
  float o = fmaf(dinv[node], a0, bias[lane]);
  out[(size_t)node * 64 + lane] = o;
}

extern "C" void kernel_launch(void* const* d_in, const int* in_sizes, int n_in,
                              void* d_out, int out_size, void* d_ws, size_t ws_size,
                              hipStream_t stream) {
  const int n = in_sizes[0] / K_DIM;   // 50000
  const int E = in_sizes[1] / 2;       // 1600000

  const float* x  = (const float*)d_in[0];
  const int*   ei = (const int*)d_in[1];
  const float* W1 = (const float*)d_in[2];
  const float* b1 = (const float*)d_in[3];
  const float* W2 = (const float*)d_in[4];
  const float* b2 = (const float*)d_in[5];
  const float* W3 = (const float*)d_in[6];
  const float* b3 = (const float*)d_in[7];
  const float* W4 = (const float*)d_in[8];
  const float* b4 = (const float*)d_in[9];
  float* out = (float*)d_out;

  char* ws = (char*)d_ws;
  size_t off = 0;
  auto alloc = [&](size_t bytes) -> void* {
    void* p = ws + off;
    off += (bytes + 255) & ~(size_t)255;
    return p;
  };
  int*    deg    = (int*)   alloc((size_t)n * 4);
  float*  dinv   = (float*) alloc((size_t)n * 4);
  int*    rowptr = (int*)   alloc((size_t)(n + 1) * 4);
  int*    cursor = (int*)   alloc((size_t)n * 4);
  int*    colidx = (int*)   alloc((size_t)(E + n) * 4);
  __half* hH     = (__half*)alloc((size_t)n * 128 * 2);  // fp16 pre-agg features
  float*  f1     = (float*) alloc((size_t)n * 128 * 4);  // fp32 post-agg features

  // CSR build
  init_deg_k<<<(n + 255) / 256, 256, 0, stream>>>(deg, n);
  count_k<<<(E + 255) / 256, 256, 0, stream>>>(ei + E, E, deg);
  scan_k<<<1, 1024, 0, stream>>>(deg, rowptr, cursor, dinv, n);
  scatter_k<<<(E + n + 255) / 256, 256, 0, stream>>>(ei, E, n, cursor, colidx);

  const int gb = (n + 63) / 64;   // gemm blocks
  const int ab = (n + 3) / 4;     // agg blocks

  // layer 1
  gemm_k<128><<<gb, 256, 0, stream>>>(x, W1, hH, n);
  agg128_k<true><<<ab, 256, 0, stream>>>(hH, rowptr, colidx, dinv, b1, f1, n);
  // layer 2
  gemm_k<128><<<gb, 256, 0, stream>>>(f1, W2, hH, n);
  agg128_k<true><<<ab, 256, 0, stream>>>(hH, rowptr, colidx, dinv, b2, f1, n);
  // layer 3
  gemm_k<128><<<gb, 256, 0, stream>>>(f1, W3, hH, n);
  agg128_k<true><<<ab, 256, 0, stream>>>(hH, rowptr, colidx, dinv, b3, f1, n);
  // layer 4 (128 -> 64, no relu)
  gemm_k<64><<<gb, 256, 0, stream>>>(f1, W4, hH, n);
  agg64_k<<<ab, 256, 0, stream>>>(hH, rowptr, colidx, dinv, b4, out, n);
}

// Round 3
// 570.753 us; speedup vs baseline: 1.7807x; 1.2175x over previous
//
#include <hip/hip_runtime.h>
#include <hip/hip_fp16.h>

constexpr int K_DIM = 128;

// ================= Bucketed CSR build =================
// bucket(d) = d >> 8 ; NBr = ceil(n/256) buckets of 256 nodes.

__global__ void zerob_k(int* __restrict__ bcount, int NBr) {
  int t = threadIdx.x;
  if (t < NBr) bcount[t] = 0;
}

// Pass A: per-bucket edge counts (LDS histogram, one global atomic per block-bucket)
__global__ __launch_bounds__(256) void bcount_k(const int* __restrict__ dst, int E,
    int* __restrict__ bcount, int NBr) {
  __shared__ int h[256];
  const int tid = threadIdx.x;
  h[tid] = 0;
  __syncthreads();
  for (int t = blockIdx.x * 256 + tid; t < E; t += gridDim.x * 256)
    atomicAdd(&h[dst[t] >> 8], 1);
  __syncthreads();
  if (tid < NBr && h[tid]) atomicAdd(&bcount[tid], h[tid]);
}

// scan bucket counts -> bstart[NBr+1], bcursor=bstart
__global__ __launch_bounds__(256) void bscan_k(const int* __restrict__ bcount,
    int* __restrict__ bstart, int* __restrict__ bcursor, int NBr) {
  __shared__ int sh[256];
  const int t = threadIdx.x;
  sh[t] = (t < NBr) ? bcount[t] : 0;
  __syncthreads();
  for (int off = 1; off < 256; off <<= 1) {
    int w = (t >= off) ? sh[t - off] : 0;
    __syncthreads();
    sh[t] += w;
    __syncthreads();
  }
  if (t < NBr) {
    int ex = t ? sh[t - 1] : 0;
    bstart[t] = ex;
    bcursor[t] = ex;
  }
  if (t == NBr - 1) bstart[NBr] = sh[t];
}

// Pass B: scatter packed records (src<<8 | dst&255) into bucket regions.
// One atomic reservation per (block,bucket); writes in ~32-record runs.
__global__ __launch_bounds__(256) void bscatter_k(const int* __restrict__ ei, int E,
    int* __restrict__ bcursor, unsigned* __restrict__ brec, int NBr) {
  __shared__ int h[256];
  __shared__ int base[256];
  const int tid = threadIdx.x;
  h[tid] = 0;
  __syncthreads();
  const int chunk = (E + gridDim.x - 1) / gridDim.x;
  const int s = blockIdx.x * chunk;
  const int e = min(E, s + chunk);
  for (int t = s + tid; t < e; t += 256) atomicAdd(&h[ei[E + t] >> 8], 1);
  __syncthreads();
  if (tid < NBr && h[tid]) base[tid] = atomicAdd(&bcursor[tid], h[tid]);
  __syncthreads();
  for (int t = s + tid; t < e; t += 256) {
    int src = ei[t];
    int d = ei[E + t];
    int bk = d >> 8;
    int p = atomicAdd(&base[bk], 1);
    brec[p] = ((unsigned)src << 8) | (unsigned)(d & 255);
  }
}

// Pass C: one block per bucket -> per-node CSR (+self loops), dinv, rowptr.
// Scattered colidx writes confined to this bucket's region (single CU -> L2-merged).
__global__ __launch_bounds__(256) void bcsr_k(const unsigned* __restrict__ brec,
    const int* __restrict__ bstart, int n, int E,
    int* __restrict__ rowptr, int* __restrict__ colidx, float* __restrict__ dinv) {
  __shared__ int s_deg[256];
  __shared__ int s_cur[256];
  __shared__ int s_lrp[257];
  const int b = blockIdx.x, tid = threadIdx.x;
  const int node0 = b << 8;
  const int LC = min(256, n - node0);
  const int rs = bstart[b], cnt = bstart[b + 1] - rs;

  s_deg[tid] = (tid < LC) ? 1 : 0;   // self loop
  __syncthreads();
  for (int i = tid; i < cnt; i += 256) atomicAdd(&s_deg[brec[rs + i] & 255], 1);
  __syncthreads();
  // inclusive scan -> s_lrp (exclusive offsets)
  s_cur[tid] = s_deg[tid];
  __syncthreads();
  for (int off = 1; off < 256; off <<= 1) {
    int w = (tid >= off) ? s_cur[tid - off] : 0;
    __syncthreads();
    s_cur[tid] += w;
    __syncthreads();
  }
  s_lrp[tid + 1] = s_cur[tid];
  if (tid == 0) s_lrp[0] = 0;
  __syncthreads();

  const int gbase = rs + node0;   // edges before bucket + self loops before bucket
  if (tid < LC) {
    int p = s_lrp[tid];
    colidx[gbase + p] = node0 + tid;      // self loop first
    s_cur[tid] = p + 1;
    rowptr[node0 + tid] = gbase + p;
    dinv[node0 + tid] = rsqrtf((float)(s_lrp[tid + 1] - p));
  }
  __syncthreads();
  for (int i = tid; i < cnt; i += 256) {
    unsigned r = brec[rs + i];
    int p = atomicAdd(&s_cur[r & 255], 1);
    colidx[gbase + p] = (int)(r >> 8);
  }
  if (b == (int)gridDim.x - 1 && tid == 0) rowptr[n] = E + n;
}

// ================= fp32 GEMM -> fp16 H =================
template<int NOUT>
__global__ __launch_bounds__(256) void gemm_k(const float* __restrict__ X,
    const float* __restrict__ W, __half* __restrict__ H, int n) {
  constexpr int KC = 32;
  constexpr int MC = (NOUT == 128) ? 8 : 4;
  __shared__ float Xs[64][KC + 1];
  __shared__ float Ws[KC][NOUT];
  const int tid = threadIdx.x;
  const int row0 = blockIdx.x * 64;
  const int rg = tid >> 4;
  const int cg = tid & 15;
  const int r0 = rg * 4;

  float acc[4][MC];
  #pragma unroll
  for (int i = 0; i < 4; ++i)
    #pragma unroll
    for (int j = 0; j < MC; ++j) acc[i][j] = 0.f;

  for (int kc = 0; kc < K_DIM; kc += KC) {
    __syncthreads();
    #pragma unroll
    for (int v = tid; v < 64 * KC / 4; v += 256) {
      int r = v / (KC / 4), c4 = v % (KC / 4);
      int gr = row0 + r;
      float4 x4 = make_float4(0.f, 0.f, 0.f, 0.f);
      if (gr < n)
        x4 = reinterpret_cast<const float4*>(X)[(size_t)gr * (K_DIM / 4) + (kc / 4) + c4];
      *reinterpret_cast<float4*>(&Xs[r][c4 * 4]) = x4;
    }
    #pragma unroll
    for (int v = tid; v < KC * NOUT / 4; v += 256) {
      int r = v / (NOUT / 4), c4 = v % (NOUT / 4);
      float4 w4 = reinterpret_cast<const float4*>(W)[(size_t)(kc + r) * (NOUT / 4) + c4];
      *reinterpret_cast<float4*>(&Ws[r][c4 * 4]) = w4;
    }
    __syncthreads();

    #pragma unroll 8
    for (int k = 0; k < KC; ++k) {
      float a[4];
      #pragma unroll
      for (int i = 0; i < 4; ++i) a[i] = Xs[r0 + i][k];
      float b[MC];
      float4 b0 = *reinterpret_cast<const float4*>(&Ws[k][cg * 4]);
      b[0] = b0.x; b[1] = b0.y; b[2] = b0.z; b[3] = b0.w;
      if constexpr (NOUT == 128) {
        float4 b1 = *reinterpret_cast<const float4*>(&Ws[k][64 + cg * 4]);
        b[4] = b1.x; b[5] = b1.y; b[6] = b1.z; b[7] = b1.w;
      }
      #pragma unroll
      for (int i = 0; i < 4; ++i)
        #pragma unroll
        for (int j = 0; j < MC; ++j)
          acc[i][j] = fmaf(a[i], b[j], acc[i][j]);
    }
  }

  #pragma unroll
  for (int i = 0; i < 4; ++i) {
    int gr = row0 + r0 + i;
    if (gr < n) {
      union { __half2 h[2]; float2 f; } u0;
      u0.h[0] = __floats2half2_rn(acc[i][0], acc[i][1]);
      u0.h[1] = __floats2half2_rn(acc[i][2], acc[i][3]);
      *reinterpret_cast<float2*>(&H[(size_t)gr * NOUT + cg * 4]) = u0.f;
      if constexpr (NOUT == 128) {
        union { __half2 h[2]; float2 f; } u1;
        u1.h[0] = __floats2half2_rn(acc[i][4], acc[i][5]);
        u1.h[1] = __floats2half2_rn(acc[i][6], acc[i][7]);
        *reinterpret_cast<float2*>(&H[(size_t)gr * NOUT + 64 + cg * 4]) = u1.f;
      }
    }
  }
}

// ================= CSR aggregation (fp16 gather, shfl-broadcast indices) ==========
template<bool RELU>
__global__ __launch_bounds__(256) void agg128_k(const __half* __restrict__ H,
    const int* __restrict__ rowptr, const int* __restrict__ colidx,
    const float* __restrict__ dinv, const float* __restrict__ bias,
    float* __restrict__ out, int n) {
  const int wave = threadIdx.x >> 6;
  const int lane = threadIdx.x & 63;
  const int node = blockIdx.x * 4 + wave;
  if (node >= n) return;
  const int s = rowptr[node], e = rowptr[node + 1];
  const __half2* H2 = reinterpret_cast<const __half2*>(H);

  float ax = 0.f, ay = 0.f;
  for (int base = s; base < e; base += 64) {
    int m = e - base;
    int c = colidx[base + ((lane < m) ? lane : 0)];
    float dv = (lane < m) ? dinv[c] : 0.f;
    int kmax = (m < 64) ? m : 64;
    #pragma unroll 4
    for (int k = 0; k < kmax; ++k) {
      int ck = __shfl(c, k);
      float dk = __shfl(dv, k);
      float2 h = __half22float2(H2[(size_t)ck * 64 + lane]);
      ax = fmaf(dk, h.x, ax);
      ay = fmaf(dk, h.y, ay);
    }
  }
  float di = dinv[node];
  float2 b2 = reinterpret_cast<const float2*>(bias)[lane];
  float ox = fmaf(di, ax, b2.x), oy = fmaf(di, ay, b2.y);
  if (RELU) { ox = fmaxf(ox, 0.f); oy = fmaxf(oy, 0.f); }
  reinterpret_cast<float2*>(out)[(size_t)node * 64 + lane] = make_float2(ox, oy);
}

__global__ __launch_bounds__(256) void agg64_k(const __half* __restrict__ H,
    const int* __restrict__ rowptr, const int* __restrict__ colidx,
    const float* __restrict__ dinv, const float* __restrict__ bias,
    float* __restrict__ out, int n) {
  const int wave = threadIdx.x >> 6;
  const int lane = threadIdx.x & 63;
  const int node = blockIdx.x * 4 + wave;
  if (node >= n) return;
  const int s = rowptr[node], e = rowptr[node + 1];

  float a0 = 0.f;
  for (int base = s; base < e; base += 64) {
    int m = e - base;
    int c = colidx[base + ((lane < m) ? lane : 0)];
    float dv = (lane < m) ? dinv[c] : 0.f;
    int kmax = (m < 64) ? m : 64;
    #pragma unroll 4
    for (int k = 0; k < kmax; ++k) {
      int ck = __shfl(c, k);
      float dk = __shfl(dv, k);
      float h = __half2float(H[(size_t)ck * 64 + lane]);
      a0 = fmaf(dk, h, a0);
    }
  }
  float o = fmaf(dinv[node], a0, bias[lane]);
  out[(size_t)node * 64 + lane] = o;
}

extern "C" void kernel_launch(void* const* d_in, const int* in_sizes, int n_in,
                              void* d_out, int out_size, void* d_ws, size_t ws_size,
                              hipStream_t stream) {
  const int n = in_sizes[0] / K_DIM;   // 50000
  const int E = in_sizes[1] / 2;       // 1600000
  const int NBr = (n + 255) >> 8;      // 196 buckets

  const float* x  = (const float*)d_in[0];
  const int*   ei = (const int*)d_in[1];
  const float* W1 = (const float*)d_in[2];
  const float* b1 = (const float*)d_in[3];
  const float* W2 = (const float*)d_in[4];
  const float* b2 = (const float*)d_in[5];
  const float* W3 = (const float*)d_in[6];
  const float* b3 = (const float*)d_in[7];
  const float* W4 = (const float*)d_in[8];
  const float* b4 = (const float*)d_in[9];
  float* out = (float*)d_out;

  char* ws = (char*)d_ws;
  size_t off = 0;
  auto alloc = [&](size_t bytes) -> void* {
    void* p = ws + off;
    off += (bytes + 255) & ~(size_t)255;
    return p;
  };
  int*      bcount  = (int*)     alloc(256 * 4);
  int*      bstart  = (int*)     alloc(257 * 4);
  int*      bcursor = (int*)     alloc(256 * 4);
  unsigned* brec    = (unsigned*)alloc((size_t)E * 4);
  int*      rowptr  = (int*)     alloc((size_t)(n + 1) * 4);
  int*      colidx  = (int*)     alloc((size_t)(E + n) * 4);
  float*    dinv    = (float*)   alloc((size_t)n * 4);
  __half*   hH      = (__half*)  alloc((size_t)n * 128 * 2);
  float*    f1      = (float*)   alloc((size_t)n * 128 * 4);

  // CSR build (bucketed)
  zerob_k<<<1, 256, 0, stream>>>(bcount, NBr);
  bcount_k<<<512, 256, 0, stream>>>(ei + E, E, bcount, NBr);
  bscan_k<<<1, 256, 0, stream>>>(bcount, bstart, bcursor, NBr);
  bscatter_k<<<256, 256, 0, stream>>>(ei, E, bcursor, brec, NBr);
  bcsr_k<<<NBr, 256, 0, stream>>>(brec, bstart, n, E, rowptr, colidx, dinv);

  const int gb = (n + 63) / 64;
  const int ab = (n + 3) / 4;

  // layer 1
  gemm_k<128><<<gb, 256, 0, stream>>>(x, W1, hH, n);
  agg128_k<true><<<ab, 256, 0, stream>>>(hH, rowptr, colidx, dinv, b1, f1, n);
  // layer 2
  gemm_k<128><<<gb, 256, 0, stream>>>(f1, W2, hH, n);
  agg128_k<true><<<ab, 256, 0, stream>>>(hH, rowptr, colidx, dinv, b2, f1, n);
  // layer 3
  gemm_k<128><<<gb, 256, 0, stream>>>(f1, W3, hH, n);
  agg128_k<true><<<ab, 256, 0, stream>>>(hH, rowptr, colidx, dinv, b3, f1, n);
  // layer 4 (128 -> 64, no relu)
  gemm_k<64><<<gb, 256, 0, stream>>>(f1, W4, hH, n);
  agg64_k<<<ab, 256, 0, stream>>>(hH, rowptr, colidx, dinv, b4, out, n);
}

// Round 4
// 326.834 us; speedup vs baseline: 3.1097x; 1.7463x over previous
//
#include <hip/hip_runtime.h>
#include <hip/hip_fp16.h>

constexpr int K_DIM = 128;

typedef short bf16x8 __attribute__((ext_vector_type(8)));
typedef float f32x4 __attribute__((ext_vector_type(4)));

#define GLOAD16(g, l) __builtin_amdgcn_global_load_lds( \
    (const __attribute__((address_space(1))) void*)(g), \
    (__attribute__((address_space(3))) void*)(l), 16, 0, 0)

__device__ __forceinline__ unsigned short f2bf(float f) {
  unsigned u = __float_as_uint(f);
  u += 0x7fff + ((u >> 16) & 1);
  return (unsigned short)(u >> 16);
}
__device__ __forceinline__ float bf2f(unsigned short s) {
  return __uint_as_float(((unsigned)s) << 16);
}

// ================= Bucketed CSR build =================
__global__ void zerob_k(int* __restrict__ bcount, int NBr) {
  int t = threadIdx.x;
  if (t < NBr) bcount[t] = 0;
}

__global__ __launch_bounds__(256) void bcount_k(const int* __restrict__ dst, int E,
    int* __restrict__ bcount, int NBr) {
  __shared__ int h[256];
  const int tid = threadIdx.x;
  h[tid] = 0;
  __syncthreads();
  for (int t = blockIdx.x * 256 + tid; t < E; t += gridDim.x * 256)
    atomicAdd(&h[dst[t] >> 8], 1);
  __syncthreads();
  if (tid < NBr && h[tid]) atomicAdd(&bcount[tid], h[tid]);
}

__global__ __launch_bounds__(256) void bscan_k(const int* __restrict__ bcount,
    int* __restrict__ bstart, int* __restrict__ bcursor, int NBr) {
  __shared__ int sh[256];
  const int t = threadIdx.x;
  sh[t] = (t < NBr) ? bcount[t] : 0;
  __syncthreads();
  for (int off = 1; off < 256; off <<= 1) {
    int w = (t >= off) ? sh[t - off] : 0;
    __syncthreads();
    sh[t] += w;
    __syncthreads();
  }
  if (t < NBr) {
    int ex = t ? sh[t - 1] : 0;
    bstart[t] = ex;
    bcursor[t] = ex;
  }
  if (t == NBr - 1) bstart[NBr] = sh[t];
}

__global__ __launch_bounds__(256) void bscatter_k(const int* __restrict__ ei, int E,
    int* __restrict__ bcursor, unsigned* __restrict__ brec, int NBr) {
  __shared__ int h[256];
  __shared__ int base[256];
  const int tid = threadIdx.x;
  h[tid] = 0;
  __syncthreads();
  const int chunk = (E + gridDim.x - 1) / gridDim.x;
  const int s = blockIdx.x * chunk;
  const int e = min(E, s + chunk);
  for (int t = s + tid; t < e; t += 256) atomicAdd(&h[ei[E + t] >> 8], 1);
  __syncthreads();
  if (tid < NBr && h[tid]) base[tid] = atomicAdd(&bcursor[tid], h[tid]);
  __syncthreads();
  for (int t = s + tid; t < e; t += 256) {
    int src = ei[t];
    int d = ei[E + t];
    int bk = d >> 8;
    int p = atomicAdd(&base[bk], 1);
    brec[p] = ((unsigned)src << 8) | (unsigned)(d & 255);
  }
}

__global__ __launch_bounds__(256) void bcsr_k(const unsigned* __restrict__ brec,
    const int* __restrict__ bstart, int n, int E,
    int* __restrict__ rowptr, int* __restrict__ colidx, float* __restrict__ dinv) {
  __shared__ int s_deg[256];
  __shared__ int s_cur[256];
  __shared__ int s_lrp[257];
  const int b = blockIdx.x, tid = threadIdx.x;
  const int node0 = b << 8;
  const int LC = min(256, n - node0);
  const int rs = bstart[b], cnt = bstart[b + 1] - rs;

  s_deg[tid] = (tid < LC) ? 1 : 0;
  __syncthreads();
  for (int i = tid; i < cnt; i += 256) atomicAdd(&s_deg[brec[rs + i] & 255], 1);
  __syncthreads();
  s_cur[tid] = s_deg[tid];
  __syncthreads();
  for (int off = 1; off < 256; off <<= 1) {
    int w = (tid >= off) ? s_cur[tid - off] : 0;
    __syncthreads();
    s_cur[tid] += w;
    __syncthreads();
  }
  s_lrp[tid + 1] = s_cur[tid];
  if (tid == 0) s_lrp[0] = 0;
  __syncthreads();

  const int gbase = rs + node0;
  if (tid < LC) {
    int p = s_lrp[tid];
    colidx[gbase + p] = node0 + tid;
    s_cur[tid] = p + 1;
    rowptr[node0 + tid] = gbase + p;
    dinv[node0 + tid] = rsqrtf((float)(s_lrp[tid + 1] - p));
  }
  __syncthreads();
  for (int i = tid; i < cnt; i += 256) {
    unsigned r = brec[rs + i];
    int p = atomicAdd(&s_cur[r & 255], 1);
    colidx[gbase + p] = (int)(r >> 8);
  }
  if (b == (int)gridDim.x - 1 && tid == 0) rowptr[n] = E + n;
}

// ================= input split: fp32 -> bf16 hi/lo =================
__global__ __launch_bounds__(256) void split_k(const float* __restrict__ x,
    unsigned* __restrict__ zh, unsigned* __restrict__ zl, long total4) {
  long t = (long)blockIdx.x * 256 + threadIdx.x;
  if (t >= total4) return;
  float4 v = reinterpret_cast<const float4*>(x)[t];
  unsigned short hx = f2bf(v.x), hy = f2bf(v.y), hz = f2bf(v.z), hw = f2bf(v.w);
  unsigned short lx = f2bf(v.x - bf2f(hx)), ly = f2bf(v.y - bf2f(hy));
  unsigned short lz = f2bf(v.z - bf2f(hz)), lw = f2bf(v.w - bf2f(hw));
  reinterpret_cast<uint2*>(zh)[t] = make_uint2((unsigned)hx | ((unsigned)hy << 16),
                                               (unsigned)hz | ((unsigned)hw << 16));
  reinterpret_cast<uint2*>(zl)[t] = make_uint2((unsigned)lx | ((unsigned)ly << 16),
                                               (unsigned)lz | ((unsigned)lw << 16));
}

// ================= W prep: fp32 W[k][c] -> bf16 hi/lo transposed Wt[c][k] ======
__global__ __launch_bounds__(256) void wprep_k(
    const float* __restrict__ W1, const float* __restrict__ W2,
    const float* __restrict__ W3, const float* __restrict__ W4,
    unsigned short* __restrict__ wth, unsigned short* __restrict__ wtl) {
  int id = blockIdx.x * 256 + threadIdx.x;
  // layers: 3 x (128x128=16384) + 1 x (128x64=8192) = 57344
  if (id >= 57344) return;
  const float* W;
  int nout, base, rem;
  if (id < 49152) {
    int l = id / 16384;
    W = (l == 0) ? W1 : (l == 1) ? W2 : W3;
    nout = 128;
    base = l * 16384;
    rem = id - base;
  } else {
    W = W4;
    nout = 64;
    base = 49152;
    rem = id - base;
  }
  int k = rem / nout, c = rem % nout;
  float w = W[k * nout + c];
  unsigned short hi = f2bf(w);
  unsigned short lo = f2bf(w - bf2f(hi));
  wth[base + c * 128 + k] = hi;
  wtl[base + c * 128 + k] = lo;
}

// ================= MFMA GEMM: H[n x NOUT] = Z @ W (3-term bf16 split) =========
// block: 256 thr (4 waves), tile 128 rows; wave: 32 rows x NOUT cols.
template<int NOUT>
__global__ __launch_bounds__(256) void gemm_mfma_k(
    const unsigned short* __restrict__ Zh, const unsigned short* __restrict__ Zl,
    const unsigned short* __restrict__ Wh, const unsigned short* __restrict__ Wl,
    __half* __restrict__ H, int n) {
  constexpr int NT = NOUT / 16;
  __shared__ unsigned short Ah[128][32];
  __shared__ unsigned short Al[128][32];
  __shared__ unsigned short Bh[NOUT][32];
  __shared__ unsigned short Bl[NOUT][32];
  const int tid = threadIdx.x;
  const int lane = tid & 63;
  const int w = tid >> 6;
  const int r16 = lane & 15;
  const int kb = lane >> 4;
  const int row0 = blockIdx.x * 128;

  f32x4 acc[2][NT];
  #pragma unroll
  for (int rg = 0; rg < 2; ++rg)
    #pragma unroll
    for (int t = 0; t < NT; ++t)
      #pragma unroll
      for (int q = 0; q < 4; ++q) acc[rg][t][q] = 0.f;

  char* AhB = (char*)&Ah[0][0];
  char* AlB = (char*)&Al[0][0];
  char* BhB = (char*)&Bh[0][0];
  char* BlB = (char*)&Bl[0][0];

  for (int kc = 0; kc < 128; kc += 32) {
    __syncthreads();
    // stage A: slot i -> row=i>>2, quarter=i&3 ; 2 instrs per plane (rows 0..63, 64..127)
    {
      int i0 = tid, i1 = tid + 256;
      int r0c = row0 + (i0 >> 2); r0c = (r0c < n) ? r0c : (n - 1);
      int r1c = row0 + (i1 >> 2); r1c = (r1c < n) ? r1c : (n - 1);
      const unsigned short* g0h = Zh + (size_t)r0c * 128 + kc + (i0 & 3) * 8;
      const unsigned short* g1h = Zh + (size_t)r1c * 128 + kc + (i1 & 3) * 8;
      const unsigned short* g0l = Zl + (size_t)r0c * 128 + kc + (i0 & 3) * 8;
      const unsigned short* g1l = Zl + (size_t)r1c * 128 + kc + (i1 & 3) * 8;
      GLOAD16(g0h, AhB + w * 1024);
      GLOAD16(g1h, AhB + 4096 + w * 1024);
      GLOAD16(g0l, AlB + w * 1024);
      GLOAD16(g1l, AlB + 4096 + w * 1024);
    }
    // stage B: slot i -> c=i>>2, quarter=i&3
    {
      int i0 = tid;
      const unsigned short* g0h = Wh + (size_t)(i0 >> 2) * 128 + kc + (i0 & 3) * 8;
      const unsigned short* g0l = Wl + (size_t)(i0 >> 2) * 128 + kc + (i0 & 3) * 8;
      GLOAD16(g0h, BhB + w * 1024);
      GLOAD16(g0l, BlB + w * 1024);
      if constexpr (NOUT == 128) {
        int i1 = tid + 256;
        const unsigned short* g1h = Wh + (size_t)(i1 >> 2) * 128 + kc + (i1 & 3) * 8;
        const unsigned short* g1l = Wl + (size_t)(i1 >> 2) * 128 + kc + (i1 & 3) * 8;
        GLOAD16(g1h, BhB + 4096 + w * 1024);
        GLOAD16(g1l, BlB + 4096 + w * 1024);
      }
    }
    __syncthreads();

    bf16x8 ah0 = *(const bf16x8*)&Ah[w * 32 + r16][kb * 8];
    bf16x8 ah1 = *(const bf16x8*)&Ah[w * 32 + 16 + r16][kb * 8];
    bf16x8 al0 = *(const bf16x8*)&Al[w * 32 + r16][kb * 8];
    bf16x8 al1 = *(const bf16x8*)&Al[w * 32 + 16 + r16][kb * 8];
    #pragma unroll
    for (int t = 0; t < NT; ++t) {
      bf16x8 bh = *(const bf16x8*)&Bh[t * 16 + r16][kb * 8];
      bf16x8 bl = *(const bf16x8*)&Bl[t * 16 + r16][kb * 8];
      acc[0][t] = __builtin_amdgcn_mfma_f32_16x16x32_bf16(ah0, bh, acc[0][t], 0, 0, 0);
      acc[0][t] = __builtin_amdgcn_mfma_f32_16x16x32_bf16(ah0, bl, acc[0][t], 0, 0, 0);
      acc[0][t] = __builtin_amdgcn_mfma_f32_16x16x32_bf16(al0, bh, acc[0][t], 0, 0, 0);
      acc[1][t] = __builtin_amdgcn_mfma_f32_16x16x32_bf16(ah1, bh, acc[1][t], 0, 0, 0);
      acc[1][t] = __builtin_amdgcn_mfma_f32_16x16x32_bf16(ah1, bl, acc[1][t], 0, 0, 0);
      acc[1][t] = __builtin_amdgcn_mfma_f32_16x16x32_bf16(al1, bh, acc[1][t], 0, 0, 0);
    }
  }

  // epilogue: raw H store as fp16 (bias/relu applied in agg)
  #pragma unroll
  for (int rg = 0; rg < 2; ++rg) {
    #pragma unroll
    for (int t = 0; t < NT; ++t) {
      int col = t * 16 + r16;
      #pragma unroll
      for (int q = 0; q < 4; ++q) {
        int grow = row0 + w * 32 + rg * 16 + kb * 4 + q;
        if (grow < n) H[(size_t)grow * NOUT + col] = __float2half(acc[rg][t][q]);
      }
    }
  }
}

// ================= CSR aggregation =================
// agg128: fp16 gather, fp32 accum, bias+relu, write bf16 hi/lo split.
__global__ __launch_bounds__(256) void agg128_k(const __half* __restrict__ H,
    const int* __restrict__ rowptr, const int* __restrict__ colidx,
    const float* __restrict__ dinv, const float* __restrict__ bias,
    unsigned* __restrict__ Zh, unsigned* __restrict__ Zl, int n) {
  const int wave = threadIdx.x >> 6;
  const int lane = threadIdx.x & 63;
  const int node = blockIdx.x * 4 + wave;
  if (node >= n) return;
  const int s = rowptr[node], e = rowptr[node + 1];
  const __half2* H2 = reinterpret_cast<const __half2*>(H);

  float ax = 0.f, ay = 0.f;
  int m = e - s;
  int c = colidx[s + ((lane < m) ? lane : 0)];
  float dv = (lane < m) ? dinv[c] : 0.f;
  for (int base = s; base < e;) {
    int nb = base + 64;
    int kmax = e - base;
    if (kmax > 64) kmax = 64;
    int c_n = 0;
    float dv_n = 0.f;
    if (nb < e) {
      int m2 = e - nb;
      c_n = colidx[nb + ((lane < m2) ? lane : 0)];
      dv_n = (lane < m2) ? dinv[c_n] : 0.f;
    }
    int k = 0;
    for (; k + 7 < kmax; k += 8) {
      int cc[8];
      float dd[8];
      float2 hh[8];
      #pragma unroll
      for (int u = 0; u < 8; ++u) { cc[u] = __shfl(c, k + u); dd[u] = __shfl(dv, k + u); }
      #pragma unroll
      for (int u = 0; u < 8; ++u) hh[u] = __half22float2(H2[(size_t)cc[u] * 64 + lane]);
      #pragma unroll
      for (int u = 0; u < 8; ++u) { ax = fmaf(dd[u], hh[u].x, ax); ay = fmaf(dd[u], hh[u].y, ay); }
    }
    for (; k < kmax; ++k) {
      int ck = __shfl(c, k);
      float dk = __shfl(dv, k);
      float2 h = __half22float2(H2[(size_t)ck * 64 + lane]);
      ax = fmaf(dk, h.x, ax);
      ay = fmaf(dk, h.y, ay);
    }
    base = nb;
    c = c_n;
    dv = dv_n;
  }
  float di = dinv[node];
  float2 b2 = reinterpret_cast<const float2*>(bias)[lane];
  float ox = fmaxf(fmaf(di, ax, b2.x), 0.f);
  float oy = fmaxf(fmaf(di, ay, b2.y), 0.f);
  unsigned short hx = f2bf(ox), hy = f2bf(oy);
  unsigned short lx = f2bf(ox - bf2f(hx)), ly = f2bf(oy - bf2f(hy));
  Zh[(size_t)node * 64 + lane] = (unsigned)hx | ((unsigned)hy << 16);
  Zl[(size_t)node * 64 + lane] = (unsigned)lx | ((unsigned)ly << 16);
}

// agg64: final layer, fp32 out, no relu.
__global__ __launch_bounds__(256) void agg64_k(const __half* __restrict__ H,
    const int* __restrict__ rowptr, const int* __restrict__ colidx,
    const float* __restrict__ dinv, const float* __restrict__ bias,
    float* __restrict__ out, int n) {
  const int wave = threadIdx.x >> 6;
  const int lane = threadIdx.x & 63;
  const int node = blockIdx.x * 4 + wave;
  if (node >= n) return;
  const int s = rowptr[node], e = rowptr[node + 1];

  float a0 = 0.f;
  int m = e - s;
  int c = colidx[s + ((lane < m) ? lane : 0)];
  float dv = (lane < m) ? dinv[c] : 0.f;
  for (int base = s; base < e;) {
    int nb = base + 64;
    int kmax = e - base;
    if (kmax > 64) kmax = 64;
    int c_n = 0;
    float dv_n = 0.f;
    if (nb < e) {
      int m2 = e - nb;
      c_n = colidx[nb + ((lane < m2) ? lane : 0)];
      dv_n = (lane < m2) ? dinv[c_n] : 0.f;
    }
    int k = 0;
    for (; k + 7 < kmax; k += 8) {
      int cc[8];
      float dd[8];
      float hh[8];
      #pragma unroll
      for (int u = 0; u < 8; ++u) { cc[u] = __shfl(c, k + u); dd[u] = __shfl(dv, k + u); }
      #pragma unroll
      for (int u = 0; u < 8; ++u) hh[u] = __half2float(H[(size_t)cc[u] * 64 + lane]);
      #pragma unroll
      for (int u = 0; u < 8; ++u) a0 = fmaf(dd[u], hh[u], a0);
    }
    for (; k < kmax; ++k) {
      int ck = __shfl(c, k);
      float dk = __shfl(dv, k);
      a0 = fmaf(dk, __half2float(H[(size_t)ck * 64 + lane]), a0);
    }
    base = nb;
    c = c_n;
    dv = dv_n;
  }
  out[(size_t)node * 64 + lane] = fmaf(dinv[node], a0, bias[lane]);
}

extern "C" void kernel_launch(void* const* d_in, const int* in_sizes, int n_in,
                              void* d_out, int out_size, void* d_ws, size_t ws_size,
                              hipStream_t stream) {
  const int n = in_sizes[0] / K_DIM;   // 50000
  const int E = in_sizes[1] / 2;       // 1600000
  const int NBr = (n + 255) >> 8;

  const float* x  = (const float*)d_in[0];
  const int*   ei = (const int*)d_in[1];
  const float* W1 = (const float*)d_in[2];
  const float* b1 = (const float*)d_in[3];
  const float* W2 = (const float*)d_in[4];
  const float* b2 = (const float*)d_in[5];
  const float* W3 = (const float*)d_in[6];
  const float* b3 = (const float*)d_in[7];
  const float* W4 = (const float*)d_in[8];
  const float* b4 = (const float*)d_in[9];
  float* out = (float*)d_out;

  char* ws = (char*)d_ws;
  size_t off = 0;
  auto alloc = [&](size_t bytes) -> void* {
    void* p = ws + off;
    off += (bytes + 255) & ~(size_t)255;
    return p;
  };
  int*      bcount  = (int*)     alloc(256 * 4);
  int*      bstart  = (int*)     alloc(257 * 4);
  int*      bcursor = (int*)     alloc(256 * 4);
  unsigned* brec    = (unsigned*)alloc((size_t)E * 4);
  int*      rowptr  = (int*)     alloc((size_t)(n + 1) * 4);
  int*      colidx  = (int*)     alloc((size_t)(E + n) * 4);
  float*    dinv    = (float*)   alloc((size_t)n * 4);
  unsigned short* Zh = (unsigned short*)alloc((size_t)n * 128 * 2);
  unsigned short* Zl = (unsigned short*)alloc((size_t)n * 128 * 2);
  __half*   hH      = (__half*)  alloc((size_t)n * 128 * 2);
  unsigned short* wth = (unsigned short*)alloc((size_t)57344 * 2);
  unsigned short* wtl = (unsigned short*)alloc((size_t)57344 * 2);

  // CSR build
  zerob_k<<<1, 256, 0, stream>>>(bcount, NBr);
  bcount_k<<<512, 256, 0, stream>>>(ei + E, E, bcount, NBr);
  bscan_k<<<1, 256, 0, stream>>>(bcount, bstart, bcursor, NBr);
  bscatter_k<<<256, 256, 0, stream>>>(ei, E, bcursor, brec, NBr);
  bcsr_k<<<NBr, 256, 0, stream>>>(brec, bstart, n, E, rowptr, colidx, dinv);

  // input split + weight prep
  const long total4 = (long)n * 32;
  split_k<<<(int)((total4 + 255) / 256), 256, 0, stream>>>(x, (unsigned*)Zh, (unsigned*)Zl, total4);
  wprep_k<<<224, 256, 0, stream>>>(W1, W2, W3, W4, wth, wtl);

  const int gb = (n + 127) / 128;
  const int ab = (n + 3) / 4;

  // layer 1
  gemm_mfma_k<128><<<gb, 256, 0, stream>>>(Zh, Zl, wth, wtl, hH, n);
  agg128_k<<<ab, 256, 0, stream>>>(hH, rowptr, colidx, dinv, b1, (unsigned*)Zh, (unsigned*)Zl, n);
  // layer 2
  gemm_mfma_k<128><<<gb, 256, 0, stream>>>(Zh, Zl, wth + 16384, wtl + 16384, hH, n);
  agg128_k<<<ab, 256, 0, stream>>>(hH, rowptr, colidx, dinv, b2, (unsigned*)Zh, (unsigned*)Zl, n);
  // layer 3
  gemm_mfma_k<128><<<gb, 256, 0, stream>>>(Zh, Zl, wth + 32768, wtl + 32768, hH, n);
  agg128_k<<<ab, 256, 0, stream>>>(hH, rowptr, colidx, dinv, b3, (unsigned*)Zh, (unsigned*)Zl, n);
  // layer 4 (128 -> 64)
  gemm_mfma_k<64><<<gb, 256, 0, stream>>>(Zh, Zl, wth + 49152, wtl + 49152, hH, n);
  agg64_k<<<ab, 256, 0, stream>>>(hH, rowptr, colidx, dinv, b4, out, n);
}